// Round 6
// baseline (27.498 us; speedup 1.0000x reference)
//
#include <hip/hip_runtime.h>
#include <hip/hip_bf16.h>

#define BB 4
#define NN 256
#define KK 32
#define DD 32
#define HH 8
#define NROWS 1024            // proj rows: e = 1..1024 stored at e-1
#define NPTS (BB * NN * NN)   // 262144
#define NNSQ (NN * NN)        // 65536
#define TPB 1024              // threads (= points) per block
#define NBLK (NPTS / TPB)     // 256 blocks = 1 per CU
#define NPH 16                // phases; phase p handles hops 2p, 2p+1
#define SLICE_US (NROWS * HH) // 8192 ushorts = 16KB per k-slice
#define IPAD 4

typedef __attribute__((ext_vector_type(8))) unsigned short ushort8;
typedef __attribute__((ext_vector_type(4))) int iv4;
typedef __attribute__((ext_vector_type(4))) float fv4;

#define LGKM0 asm volatile("s_waitcnt lgkmcnt(0)" ::: "memory")
#define BAR   __builtin_amdgcn_s_barrier()

__device__ __forceinline__ unsigned short f2bf(float f) {
    unsigned u = __float_as_uint(f);
    unsigned r = (u + 0x7FFFu + ((u >> 16) & 1u)) >> 16;
    return (unsigned short)r;
}

// ---------------------------------------------------------------------------
// Kernel A: proj[k][e-1][h] = sum_d feat[e][d] * W[k][d][h]   (bf16, e=1..1024)
// ---------------------------------------------------------------------------
__global__ __launch_bounds__(256) void build_proj_bf16(
    const float* __restrict__ feat,    // [1025][32]
    const float* __restrict__ w,       // [32][256] (d*8+h)
    unsigned short* __restrict__ proj) // [32][1024][8]
{
    int t  = blockIdx.x * 256 + threadIdx.x;  // 0..32767
    int k  = t >> 10;                         // uniform per block
    int e  = (t & 1023) + 1;

    const float* frow = feat + (size_t)e * DD;
    const float* wrow = w + (size_t)k * DD * HH;

    float acc[HH];
#pragma unroll
    for (int h = 0; h < HH; ++h) acc[h] = 0.0f;

#pragma unroll
    for (int d = 0; d < DD; ++d) {
        float f = frow[d];
#pragma unroll
        for (int h = 0; h < HH; ++h) acc[h] = fmaf(f, wrow[d * HH + h], acc[h]);
    }

    ushort8 o;
#pragma unroll
    for (int h = 0; h < HH; ++h) o[h] = f2bf(acc[h]);
    *(ushort8*)(proj + (size_t)t * HH) = o;
}

// ---------------------------------------------------------------------------
// Kernel B v6: fully software-pipelined, one raw barrier per phase.
//  - tbuf: double-buffered 32KB phase slices (2 hops), reg-staged (T14)
//  - ibuf: double-buffered packed (e0,e1) index pairs, refilled in 4 chunks
//    via coalesced iv4 loads -> idx HBM streaming overlaps the whole loop
//  - compiler-managed counted vmcnt (no __syncthreads, no drains)
// E = ints per index element (2 = int64 input, 1 = int32).
// ---------------------------------------------------------------------------
template <int E>
__global__ __launch_bounds__(TPB) void attn_bias_v6(
    const int* __restrict__ sp,               // [NPTS] (*E)
    const int* __restrict__ ei,               // [NPTS*KK] (*E)
    const float* __restrict__ semb,           // [512][8]
    const unsigned short* __restrict__ proj,  // [32][1024][8] bf16
    float* __restrict__ out)                  // [BB][HH][NNSQ]
{
    __shared__ __align__(16) unsigned short tbuf[2][2 * SLICE_US]; // 64KB
    __shared__ unsigned int ibuf[2][4][NROWS + IPAD];              // ~33KB

    const int tid = threadIdx.x;
    const int p0  = blockIdx.x * TPB;

    const fv4* P4  = (const fv4*)proj;   // slice s = P4[s*1024 + i]
    const iv4* EI4 = (const iv4*)ei;
    const size_t bi4 = (size_t)p0 * (8 * E);   // iv4s per point = 8E

    fv4 S0, S1;          // staging regs: one phase's 2 slices (32B/thread)
    iv4 cv[4];           // chunk regs: E=2 -> 4 iv4, E=1 -> 2 iv4

    auto issueS = [&](int ph) {
        S0 = P4[(size_t)(2 * ph)     * 1024 + tid];
        S1 = P4[(size_t)(2 * ph + 1) * 1024 + tid];
    };
    auto writeS = [&](int nb) {
        *(fv4*)&tbuf[nb][tid * 8]            = S0;
        *(fv4*)&tbuf[nb][SLICE_US + tid * 8] = S1;
    };
    // chunk g covers hop-pairs 4g..4g+3 (phases 4g..4g+3)
    auto issueC = [&](int g) {
        if (E == 2) {
#pragma unroll
            for (int c = 0; c < 4; ++c) {
                int j = c * TPB + tid, pt = j >> 2, q = j & 3;
                cv[c] = EI4[bi4 + (size_t)pt * 16 + 4 * g + q];
            }
        } else {
#pragma unroll
            for (int c = 0; c < 2; ++c) {
                int j = c * TPB + tid, pt = j >> 1, q = j & 1;
                cv[c] = EI4[bi4 + (size_t)pt * 8 + 2 * g + q];
            }
        }
    };
    auto writeC = [&](int nb) {
        if (E == 2) {
#pragma unroll
            for (int c = 0; c < 4; ++c) {
                int j = c * TPB + tid, pt = j >> 2, q = j & 3;
                unsigned pk = ((unsigned)cv[c].x & 0xffffu) |
                              (((unsigned)cv[c].z & 0xffffu) << 16);
                ibuf[nb][q][pt] = pk;   // pair row q = hops 2q,2q+1 of chunk
            }
        } else {
#pragma unroll
            for (int c = 0; c < 2; ++c) {
                int j = c * TPB + tid, pt = j >> 1, q = j & 1;
                ibuf[nb][q * 2][pt] = ((unsigned)cv[c].x & 0xffffu) |
                                      (((unsigned)cv[c].y & 0xffffu) << 16);
                ibuf[nb][q * 2 + 1][pt] = ((unsigned)cv[c].z & 0xffffu) |
                                          (((unsigned)cv[c].w & 0xffffu) << 16);
            }
        }
    };

    // ---------------- prologue ----------------
    issueS(0);                 // slices 0,1
    issueC(0);                 // chunk 0
    const int pg = p0 + tid;
    int s = (E == 2) ? (int)((const long long*)sp)[pg] : sp[pg];  // held 1 reg

    writeS(0);                 // compiler inserts counted vmcnt for S
    issueS(1);
    writeC(0);                 // chunk 0 -> ibuf[0]
    issueC(1);                 // chunk 1 in flight across phases 0..2
    LGKM0;
    BAR;

    float acc[HH];
#pragma unroll
    for (int h = 0; h < HH; ++h) acc[h] = 0.0f;
    int cnt = 0;

    // ---------------- main loop: one barrier per phase ----------------
#pragma unroll 1
    for (int ph = 0; ph < NPH; ++ph) {
        const int g = ph >> 2;

        unsigned pr = ibuf[g & 1][ph & 3][tid];
        int e0 = pr & 0xffffu;
        int e1 = pr >> 16;
        int r0 = e0 ? (e0 - 1) : 0;
        int r1 = e1 ? (e1 - 1) : 0;
        float m0 = e0 ? 1.0f : 0.0f;
        float m1 = e1 ? 1.0f : 0.0f;
        cnt += (e0 != 0) + (e1 != 0);

        const unsigned short* tb = tbuf[ph & 1];
        ushort8 w0 = *(const ushort8*)&tb[r0 * 8];
        ushort8 w1 = *(const ushort8*)&tb[SLICE_US + r1 * 8];
#pragma unroll
        for (int h = 0; h < HH; ++h) {
            acc[h] = fmaf(m0, __uint_as_float(((unsigned)w0[h]) << 16), acc[h]);
            acc[h] = fmaf(m1, __uint_as_float(((unsigned)w1[h]) << 16), acc[h]);
        }

        if (ph < NPH - 1) {
            writeS((ph + 1) & 1);            // counted vmcnt (issued 1 phase ago)
            if (ph < NPH - 2) issueS(ph + 2);
            if ((ph & 3) == 3 && ph < 12) {  // ph = 3, 7, 11
                writeC((g + 1) & 1);         // chunk g+1 (issued ~4 phases ago)
                if (ph < 8) issueC(g + 2);   // chunks 2, 3
            }
            LGKM0;
            BAR;
        }
    }

    // ---------------- epilogue: spatial bias + write ----------------
    const float4* srow = (const float4*)(semb + (size_t)s * HH);
    float4 s0v = srow[0], s1v = srow[1];
    float sb[HH] = {s0v.x, s0v.y, s0v.z, s0v.w, s1v.x, s1v.y, s1v.z, s1v.w};

    float inv = 1.0f / (float)(cnt ? cnt : 1);
    float* o = out + (size_t)(pg >> 16) * (HH * NNSQ) + (pg & (NNSQ - 1));
#pragma unroll
    for (int h = 0; h < HH; ++h)
        o[(size_t)h * NNSQ] = sb[h] + acc[h] * inv;
}

extern "C" void kernel_launch(void* const* d_in, const int* in_sizes, int n_in,
                              void* d_out, int out_size, void* d_ws, size_t ws_size,
                              hipStream_t stream) {
    const int*   sp = (const int*)d_in[0];    // spatial_pos  [4,256,256]
    const int*   ei = (const int*)d_in[1];    // edge_input   [4,256,256,32]
    const float* se = (const float*)d_in[2];  // spatial_emb  [512,8]
    const float* fe = (const float*)d_in[3];  // edge_feat_emb[1025,32]
    const float* pw = (const float*)d_in[4];  // edge_pos_emb [32,256]
    float* out = (float*)d_out;

    const bool i64 = (in_sizes[0] == 2 * NPTS);
    unsigned short* proj = (unsigned short*)d_ws;   // 32*1024*8*2 = 512KB

    build_proj_bf16<<<128, 256, 0, stream>>>(fe, pw, proj);

    if (i64) attn_bias_v6<2><<<NBLK, TPB, 0, stream>>>(sp, ei, se, proj, out);
    else     attn_bias_v6<1><<<NBLK, TPB, 0, stream>>>(sp, ei, se, proj, out);
}

// Round 8
// 25.814 us; speedup vs baseline: 1.0653x; 1.0653x over previous
//
#include <hip/hip_runtime.h>
#include <hip/hip_bf16.h>

#define BB 4
#define NN 256
#define KK 32
#define DD 32
#define HH 8
#define NROWS 1024            // proj rows: e = 1..1024 stored at e-1
#define NPTS (BB * NN * NN)   // 262144
#define NNSQ (NN * NN)        // 65536
#define TPB 1024              // threads (= points) per block
#define NBLK (NPTS / TPB)     // 256 blocks = 1 per CU
#define SLICE_US (NROWS * HH) // 8192 ushorts = 16KB per k-slice
#define SLOT_US  (2 * SLICE_US)

typedef __attribute__((ext_vector_type(8))) unsigned short ushort8;
typedef __attribute__((ext_vector_type(4))) int iv4;

#define FENCE  asm volatile("" ::: "memory")
#define LGKM0  asm volatile("s_waitcnt lgkmcnt(0)" ::: "memory")
#define BAR    __builtin_amdgcn_s_barrier()
#define VMW(n) asm volatile("s_waitcnt vmcnt(" #n ")" ::: "memory")

__device__ __forceinline__ unsigned short f2bf(float f) {
    unsigned u = __float_as_uint(f);
    unsigned r = (u + 0x7FFFu + ((u >> 16) & 1u)) >> 16;
    return (unsigned short)r;
}

__device__ __forceinline__ void gload16(const void* g, void* l) {
    __builtin_amdgcn_global_load_lds(
        (const __attribute__((address_space(1))) void*)g,
        (__attribute__((address_space(3))) void*)l,
        16, 0, 0);
}

// ---------------------------------------------------------------------------
// Kernel A: proj[k][e-1][h] = sum_d feat[e][d] * W[k][d][h]   (bf16, e=1..1024)
// ---------------------------------------------------------------------------
__global__ __launch_bounds__(256) void build_proj_bf16(
    const float* __restrict__ feat,    // [1025][32]
    const float* __restrict__ w,       // [32][256] (d*8+h)
    unsigned short* __restrict__ proj) // [32][1024][8]
{
    int t  = blockIdx.x * 256 + threadIdx.x;  // 0..32767
    int k  = t >> 10;                         // uniform per block
    int e  = (t & 1023) + 1;

    const float* frow = feat + (size_t)e * DD;
    const float* wrow = w + (size_t)k * DD * HH;

    float acc[HH];
#pragma unroll
    for (int h = 0; h < HH; ++h) acc[h] = 0.0f;

#pragma unroll
    for (int d = 0; d < DD; ++d) {
        float f = frow[d];
#pragma unroll
        for (int h = 0; h < HH; ++h) acc[h] = fmaf(f, wrow[d * HH + h], acc[h]);
    }

    ushort8 o;
#pragma unroll
    for (int h = 0; h < HH; ++h) o[h] = f2bf(acc[h]);
    *(ushort8*)(proj + (size_t)t * HH) = o;
}

// ---------------------------------------------------------------------------
// Kernel B v8: identical to v7 except the writeC buffer-index fix.
// chunk g lives in ibuf[g & 1]: writeC(0) at ph7 (chunk2), writeC(1) at ph11
// (chunk3). v7 passed 2/3 -> OOB LDS write corrupting tbuf/ibuf.
// E = ints per index element (2 = int64 input, 1 = int32).
// ---------------------------------------------------------------------------
template <int E>
__global__ __launch_bounds__(TPB) void attn_bias_v8(
    const int* __restrict__ sp,               // [NPTS] (*E)
    const int* __restrict__ ei,               // [NPTS*KK] (*E)
    const float* __restrict__ semb,           // [512][8]
    const unsigned short* __restrict__ proj,  // [32][1024][8] bf16
    float* __restrict__ out)                  // [BB][HH][NNSQ]
{
    __shared__ __align__(16) unsigned short tbuf[3 * SLOT_US]; // 96KB ring
    __shared__ __align__(16) unsigned short zrow[8];           // zero row (e==0)
    __shared__ unsigned int ibuf[2][4][NROWS + 4];             // ~33KB

    const int tid = threadIdx.x;
    const int p0  = blockIdx.x * TPB;
    const int pg  = p0 + tid;

    constexpr int NC = (E == 2) ? 4 : 2;
    const iv4* EI4 = (const iv4*)ei;
    const size_t bi4 = (size_t)p0 * (8 * E);   // iv4s per point = 8E

    iv4 cv[NC];   // chunk staging regs (compile-time indexed)

    auto issueC = [&](int g) {
#pragma unroll
        for (int c = 0; c < NC; ++c) {
            if (E == 2) {
                int j = c * TPB + tid, pt = j >> 2, q = j & 3;
                cv[c] = EI4[bi4 + (size_t)pt * 16 + 4 * g + q];
            } else {
                int j = c * TPB + tid, pt = j >> 1, q = j & 1;
                cv[c] = EI4[bi4 + (size_t)pt * 8 + 2 * g + q];
            }
        }
    };
    auto writeC = [&](int nb) {   // nb = ibuf double-buffer index (0/1) ONLY
#pragma unroll
        for (int c = 0; c < NC; ++c) {
            if (E == 2) {
                int j = c * TPB + tid, pt = j >> 2, q = j & 3;
                ibuf[nb][q][pt] = ((unsigned)cv[c].x & 0xffffu) |
                                  ((unsigned)cv[c].z << 16);
            } else {
                int j = c * TPB + tid, pt = j >> 1, q = j & 1;
                ibuf[nb][2 * q][pt] = ((unsigned)cv[c].x & 0xffffu) |
                                      ((unsigned)cv[c].y << 16);
                ibuf[nb][2 * q + 1][pt] = ((unsigned)cv[c].z & 0xffffu) |
                                          ((unsigned)cv[c].w << 16);
            }
        }
    };
    auto stage2 = [&](int phn, int slot) {   // stage phase phn's 2 slices
        gload16(proj + (size_t)(2 * phn) * SLICE_US + tid * HH,
                &tbuf[slot * SLOT_US + tid * HH]);
        gload16(proj + (size_t)(2 * phn + 1) * SLICE_US + tid * HH,
                &tbuf[slot * SLOT_US + SLICE_US + tid * HH]);
    };

    float acc[HH];
#pragma unroll
    for (int h = 0; h < HH; ++h) acc[h] = 0.0f;
    int cnt = 0;

    auto dohops = [&](int slot, int gsel, int q) {
        unsigned pr = ibuf[gsel][q][tid];
        int e0 = pr & 0xffffu;
        int e1 = pr >> 16;
        cnt += (e0 != 0) + (e1 != 0);
        const unsigned short* tb = &tbuf[slot * SLOT_US];
        const unsigned short* a0 = e0 ? tb + (e0 - 1) * HH : zrow;
        const unsigned short* a1 = e1 ? tb + SLICE_US + (e1 - 1) * HH : zrow;
        ushort8 w0 = *(const ushort8*)a0;
        ushort8 w1 = *(const ushort8*)a1;
#pragma unroll
        for (int h = 0; h < HH; ++h) {
            acc[h] += __uint_as_float(((unsigned)w0[h]) << 16);
            acc[h] += __uint_as_float(((unsigned)w1[h]) << 16);
        }
    };

#define VMWA do { if constexpr (E == 2) VMW(6); else VMW(4); } while (0)
#define ENDPH do { FENCE; VMW(2); LGKM0; BAR; } while (0)

    // ---------------- prologue ----------------
    int sv = (E == 2) ? (int)((const long long*)sp)[pg] : sp[pg];
    FENCE;
    issueC(0);
    FENCE;
    stage2(0, 0);          // slices 0,1 -> slot0
    stage2(1, 1);          // slices 2,3 -> slot1
    if (tid == 0) *(float4*)zrow = make_float4(0.f, 0.f, 0.f, 0.f);
    FENCE;
    writeC(0);             // chunk 0 -> ibuf[0]
    issueC(1);
    FENCE;
    VMWA; LGKM0; BAR;      // drain slot0 gloads; keep slot1 + chunk1

    // ---------------- 16 hand-unrolled phases ----------------
    stage2(2, 2);  FENCE; dohops(0, 0, 0); FENCE; VMWA; LGKM0; BAR;   // ph0
    stage2(3, 0);  FENCE; dohops(1, 0, 1); ENDPH;                     // ph1
    stage2(4, 1);  FENCE; dohops(2, 0, 2); ENDPH;                     // ph2
    stage2(5, 2);  FENCE; dohops(0, 0, 3); writeC(1); issueC(2);      // chunk1 -> ibuf[1]
                   FENCE; VMWA; LGKM0; BAR;                           // ph3
    stage2(6, 0);  FENCE; dohops(1, 1, 0); FENCE; VMWA; LGKM0; BAR;   // ph4
    stage2(7, 1);  FENCE; dohops(2, 1, 1); ENDPH;                     // ph5
    stage2(8, 2);  FENCE; dohops(0, 1, 2); ENDPH;                     // ph6
    stage2(9, 0);  FENCE; dohops(1, 1, 3); writeC(0); issueC(3);      // chunk2 -> ibuf[0]  (FIX)
                   FENCE; VMWA; LGKM0; BAR;                           // ph7
    stage2(10, 1); FENCE; dohops(2, 0, 0); FENCE; VMWA; LGKM0; BAR;   // ph8
    stage2(11, 2); FENCE; dohops(0, 0, 1); ENDPH;                     // ph9
    stage2(12, 0); FENCE; dohops(1, 0, 2); ENDPH;                     // ph10
    stage2(13, 1); FENCE; dohops(2, 0, 3); writeC(1); ENDPH;          // chunk3 -> ibuf[1]  (FIX) ph11
    stage2(14, 2); FENCE; dohops(0, 1, 0); ENDPH;                     // ph12
    stage2(15, 0); FENCE; dohops(1, 1, 1); ENDPH;                     // ph13
    dohops(2, 1, 2); FENCE; VMW(0); LGKM0; BAR;                       // ph14
    dohops(0, 1, 3);                                                  // ph15

    // ---------------- epilogue: spatial bias + write ----------------
    const float4* srow = (const float4*)(semb + (size_t)sv * HH);
    float4 s0v = srow[0], s1v = srow[1];
    float sb[HH] = {s0v.x, s0v.y, s0v.z, s0v.w, s1v.x, s1v.y, s1v.z, s1v.w};

    float inv = 1.0f / (float)(cnt ? cnt : 1);
    float* o = out + (size_t)(pg >> 16) * (HH * NNSQ) + (pg & (NNSQ - 1));
#pragma unroll
    for (int h = 0; h < HH; ++h)
        o[(size_t)h * NNSQ] = sb[h] + acc[h] * inv;
}

extern "C" void kernel_launch(void* const* d_in, const int* in_sizes, int n_in,
                              void* d_out, int out_size, void* d_ws, size_t ws_size,
                              hipStream_t stream) {
    const int*   sp = (const int*)d_in[0];    // spatial_pos  [4,256,256]
    const int*   ei = (const int*)d_in[1];    // edge_input   [4,256,256,32]
    const float* se = (const float*)d_in[2];  // spatial_emb  [512,8]
    const float* fe = (const float*)d_in[3];  // edge_feat_emb[1025,32]
    const float* pw = (const float*)d_in[4];  // edge_pos_emb [32,256]
    float* out = (float*)d_out;

    const bool i64 = (in_sizes[0] == 2 * NPTS);
    unsigned short* proj = (unsigned short*)d_ws;   // 32*1024*8*2 = 512KB

    build_proj_bf16<<<128, 256, 0, stream>>>(fe, pw, proj);

    if (i64) attn_bias_v8<2><<<NBLK, TPB, 0, stream>>>(sp, ei, se, proj, out);
    else     attn_bias_v8<1><<<NBLK, TPB, 0, stream>>>(sp, ei, se, proj, out);
}